// Round 5
// baseline (34.754 us; speedup 1.0000x reference)
//
#include <hip/hip_runtime.h>
#include <math.h>

#define IMG   112
#define HW    12544
#define GRID  16
#define DP    384
#define CF    128
#define CIN   512
#define COUT  128
#define KTOP  64
#define NHEADS 6
#define NBIN  2048   // 11-bit bins of the orderable key
#define CAP   2048   // candidate capacity (expected ~100-400 for Gaussian data)
#define NJ    12     // 12*1024 + 256 = 12544

// jax f32 sample position: fl32((i+0.5f)*fl32(16/112)) - 0.5f.
// (i+0.5f) and fl32(16/112) are exact f32; their real product has <=48
// significand bits, so __fmul_rn == (float)((double)a*(double)b) bit-exactly.
// __fadd_rn/__fmul_rn cannot be contracted into fma (dst=3 must give 0.0).
struct BL { int i0, i1; float w; };

__device__ __forceinline__ BL bl_coeff(int i) {
    float s = __fadd_rn(__fmul_rn((float)i + 0.5f, 16.0f / 112.0f), -0.5f);
    s = fminf(fmaxf(s, 0.0f), 15.0f);   // clamp FIRST -> clamp groups bit-identical
    int i0 = (int)s;
    if (i0 > GRID - 2) i0 = GRID - 2;
    BL r;
    r.i0 = i0;
    r.i1 = i0 + 1;
    r.w  = s - (float)i0;               // exact (Sterbenz)
    return r;
}

// Orderable transform: ascending finite float <-> ascending unsigned.
__device__ __forceinline__ unsigned ordkey(float f) {
    unsigned u = __float_as_uint(f);
    return u ^ ((u & 0x80000000u) ? 0xFFFFFFFFu : 0x80000000u);
}

// av[yi*16+xi] = {amean[yi][xi], amean[yi+1][xi]} : one b64 read -> v00,v10.
__device__ __forceinline__ unsigned bilin_key(const float2* av, int idx) {
    int y = idx / IMG, x = idx - y * IMG;
    BL by = bl_coeff(y), bx = bl_coeff(x);
    float2 a0 = av[by.i0 * GRID + bx.i0];
    float2 a1 = av[by.i0 * GRID + bx.i0 + 1];
    float top = (1.0f - bx.w) * a0.x + bx.w * a1.x;
    float bot = (1.0f - bx.w) * a0.y + bx.w * a1.y;
    float v   = (1.0f - by.w) * top + by.w * bot;
    return ordkey(v);
}

extern "C" __global__ void __launch_bounds__(1024)
topk_kernel(const float* __restrict__ attn, int* __restrict__ topk_out) {
    __shared__ float    amean[GRID * GRID];
    __shared__ float2   av[240];         // yi0 in 0..14
    __shared__ unsigned hist[8][NBIN];   // 64 KB, per-wave-pair copies
    __shared__ unsigned wtot[16];
    __shared__ unsigned s_T;
    __shared__ int      s_nc;
    __shared__ unsigned candk[CAP];
    __shared__ int      candi[CAP];

    const int b = blockIdx.x;
    const int t = threadIdx.x;
    const int lane = t & 63;
    const int wv = t >> 6;       // 0..15
    const int hc = wv >> 1;      // 8 histogram copies

    // mean over heads (linear op commutes with the linear resize)
    if (t < 256) {
        float s = 0.0f;
        for (int h = 0; h < NHEADS; ++h)
            s += attn[(((size_t)b * NHEADS + h) << 8) + t];
        amean[t] = s * (1.0f / 6.0f);
    }
    for (int i = t; i < 8 * NBIN; i += 1024) ((unsigned*)hist)[i] = 0;
    if (t == 0) s_nc = 0;
    __syncthreads();
    if (t < 240) av[t] = make_float2(amean[t], amean[t + 16]);
    __syncthreads();

    // 12.25 resized values per thread (bit-identical arithmetic). Lane->pixel
    // rotation decorrelates histogram bins within a wave.
    const int pt_ = (((t & 63) << 4) | (t >> 6)) & 1023;   // bijection on 0..1023
    unsigned lk[NJ];
    unsigned tailk = 0;
#pragma unroll
    for (int j = 0; j < NJ; ++j) {
        unsigned key = bilin_key(av, j * 1024 + pt_);
        lk[j] = key;
        atomicAdd(&hist[hc][key >> 21], 1u);
    }
    if (t < 256) {
        tailk = bilin_key(av, NJ * 1024 + t);
        atomicAdd(&hist[hc][tailk >> 21], 1u);
    }
    __syncthreads();

    // block-wide suffix scan over 2048 bins (2 bins per thread): find bin T
    // such that count(bin >= T) >= 64 > count(bin >= T+1)
    unsigned c0 = 0, c1 = 0;
    {
        const int bin0 = t * 2;
#pragma unroll
        for (int k = 0; k < 8; ++k) { c0 += hist[k][bin0]; c1 += hist[k][bin0 + 1]; }
    }
    const unsigned tot = c0 + c1;
    unsigned v = tot;   // inclusive suffix within wave
    for (int off = 1; off < 64; off <<= 1) {
        unsigned o = __shfl_down(v, off);
        if (lane + off < 64) v += o;
    }
    if (lane == 0) wtot[wv] = v;
    __syncthreads();
    unsigned add = 0;
    for (int w = wv + 1; w < 16; ++w) add += wtot[w];
    const unsigned S = v + add;          // count in bins >= t*2
    const unsigned above = S - tot;      // count in bins >= t*2+2
    const unsigned cum1 = above + c1;    // bins >= t*2+1
    if (cum1 >= KTOP && above < KTOP) s_T = (unsigned)(t * 2 + 1);
    const unsigned cum0 = cum1 + c0;     // bins >= t*2
    if (cum0 >= KTOP && cum1 < KTOP) s_T = (unsigned)(t * 2);
    __syncthreads();
    const unsigned T = s_T;

    // collect all candidates with bin >= T
#pragma unroll
    for (int j = 0; j < NJ; ++j) {
        unsigned key = lk[j];
        if ((key >> 21) >= T) {
            int sl = atomicAdd(&s_nc, 1);
            if (sl < CAP) { candk[sl] = key; candi[sl] = j * 1024 + pt_; }
        }
    }
    if (t < 256 && (tailk >> 21) >= T) {
        int sl = atomicAdd(&s_nc, 1);
        if (sl < CAP) { candk[sl] = tailk; candi[sl] = NJ * 1024 + t; }
    }
    __syncthreads();

    // exact stable rank select, 4 threads per candidate:
    // total order (key desc, idx asc) == jax.lax.top_k
    const int n = s_nc < CAP ? s_nc : CAP;
    const int q = t & 3;
    for (int c = t >> 2; c < n; c += 256) {
        unsigned myk = candk[c]; int myi = candi[c];
        int r = 0;
        for (int j2 = q; j2 < n; j2 += 4) {
            unsigned k2 = candk[j2];
            r += (k2 > myk) || (k2 == myk && candi[j2] < myi);
        }
        r += __shfl_xor(r, 1);
        r += __shfl_xor(r, 2);
        if (q == 0 && r < KTOP) topk_out[b * KTOP + r] = myi;
    }
}

// Register-tiled GEMV: 128 threads = 32 ch-quads x 4-way K-split.
// Each thread: 4 px x 4 ch accumulators; per step 4 LDS b128 + 4 w float4
// -> 64 FMA. Weights read exactly once per block, fully-consumed 64B lines.
extern "C" __global__ void __launch_bounds__(128)
feat_kernel(const float* __restrict__ lf, const float* __restrict__ pt,
            const float* __restrict__ cw, const float* __restrict__ cb,
            const float* __restrict__ bg, const float* __restrict__ bb,
            const float* __restrict__ bm, const float* __restrict__ bvr,
            const int* __restrict__ topk, float* __restrict__ out) {
    const int g = blockIdx.x;   // pixel group: 4 topk pixels per block
    const int b = blockIdx.y;
    const int t = threadIdx.x;  // 0..127
    const int lane = t & 63;
    const int wv = t >> 6;
    __shared__ __align__(16) float comb[4][CIN];   // 8 KB
    __shared__ __align__(16) float vmat[4][COUT];
    __shared__ float snrm[4];
    __shared__ int   sidx[4];
    if (t < 4) sidx[t] = topk[b * KTOP + g * 4 + t];
    __syncthreads();

    // stage combined features for 4 pixels (bilinear coeffs hoisted per px)
    int   yi0[4], xi0[4];
    float wyv[4], wxv[4];
#pragma unroll
    for (int px = 0; px < 4; ++px) {
        const int idx = sidx[px];
        const int y = idx / IMG, x = idx - y * IMG;
        BL by = bl_coeff(y), bx = bl_coeff(x);
        yi0[px] = by.i0; xi0[px] = bx.i0; wyv[px] = by.w; wxv[px] = bx.w;
    }
    const float* ptb = pt + (size_t)b * 256 * DP;
#pragma unroll
    for (int ci = 0; ci < 4; ++ci) {
        const int c = t + ci * 128;
#pragma unroll
        for (int px = 0; px < 4; ++px) {
            float val;
            if (c < DP) {
                const int base = yi0[px] * GRID + xi0[px];
                float p00 = ptb[(size_t)base * DP + c];
                float p01 = ptb[(size_t)(base + 1) * DP + c];
                float p10 = ptb[(size_t)(base + GRID) * DP + c];
                float p11 = ptb[(size_t)(base + GRID + 1) * DP + c];
                float top = (1.0f - wxv[px]) * p00 + wxv[px] * p01;
                float bot = (1.0f - wxv[px]) * p10 + wxv[px] * p11;
                val = (1.0f - wyv[px]) * top + wyv[px] * bot;
            } else {
                val = lf[((size_t)b * CF + (c - DP)) * HW + sidx[px]];
            }
            comb[px][c] = val;
        }
    }
    __syncthreads();

    // GEMV: thread (c4, l): channels c4*4..+3, K-slices c = i*16 + l*4
    const int c4 = t >> 2, l = t & 3;
    float acc[4][4];
#pragma unroll
    for (int p = 0; p < 4; ++p)
#pragma unroll
        for (int j = 0; j < 4; ++j) acc[p][j] = 0.0f;

    const float* wbase = cw + (size_t)c4 * 4 * CIN + l * 4;
#pragma unroll 8
    for (int i = 0; i < 32; ++i) {
        const int c = i * 16;
        float4 w0 = *(const float4*)(wbase + c);
        float4 w1 = *(const float4*)(wbase + CIN + c);
        float4 w2 = *(const float4*)(wbase + 2 * CIN + c);
        float4 w3 = *(const float4*)(wbase + 3 * CIN + c);
        float4 cb0 = *(const float4*)(&comb[0][c + l * 4]);
        float4 cb1 = *(const float4*)(&comb[1][c + l * 4]);
        float4 cb2 = *(const float4*)(&comb[2][c + l * 4]);
        float4 cb3 = *(const float4*)(&comb[3][c + l * 4]);
#define DOT4(W, C) ((W).x * (C).x + (W).y * (C).y + (W).z * (C).z + (W).w * (C).w)
        acc[0][0] += DOT4(w0, cb0); acc[0][1] += DOT4(w1, cb0);
        acc[0][2] += DOT4(w2, cb0); acc[0][3] += DOT4(w3, cb0);
        acc[1][0] += DOT4(w0, cb1); acc[1][1] += DOT4(w1, cb1);
        acc[1][2] += DOT4(w2, cb1); acc[1][3] += DOT4(w3, cb1);
        acc[2][0] += DOT4(w0, cb2); acc[2][1] += DOT4(w1, cb2);
        acc[2][2] += DOT4(w2, cb2); acc[2][3] += DOT4(w3, cb2);
        acc[3][0] += DOT4(w0, cb3); acc[3][1] += DOT4(w1, cb3);
        acc[3][2] += DOT4(w2, cb3); acc[3][3] += DOT4(w3, cb3);
#undef DOT4
    }
    // K-split reduce across l (quad-perm DPP shuffles, VALU-only)
#pragma unroll
    for (int p = 0; p < 4; ++p)
#pragma unroll
        for (int j = 0; j < 4; ++j) {
            acc[p][j] += __shfl_xor(acc[p][j], 1);
            acc[p][j] += __shfl_xor(acc[p][j], 2);
        }
    if (l == 0) {
#pragma unroll
        for (int j = 0; j < 4; ++j) {
            const int ch = c4 * 4 + j;
            float scale = bg[ch] / sqrtf(bvr[ch] + 1e-5f);
            float shift = bb[ch] - bm[ch] * scale;
            float base  = cb[ch];
#pragma unroll
            for (int p = 0; p < 4; ++p)
                vmat[p][ch] = fmaxf((base + acc[p][j]) * scale + shift, 0.0f);
        }
    }
    __syncthreads();

    // L2 norm per pixel (2 waves x 2 px)
    if (wv < 2) {
#pragma unroll
        for (int pp = 0; pp < 2; ++pp) {
            const int px = wv * 2 + pp;
            float x0 = vmat[px][lane], x1 = vmat[px][lane + 64];
            float ss = x0 * x0 + x1 * x1;
            for (int off = 32; off > 0; off >>= 1) ss += __shfl_xor(ss, off);
            if (lane == 0) snrm[px] = sqrtf(ss);
        }
    }
    __syncthreads();

    // thread = channel; one float4 covers the 4 consecutive k slots
    {
        float4 o;
        o.x = vmat[0][t] / fmaxf(snrm[0], 1e-12f);
        o.y = vmat[1][t] / fmaxf(snrm[1], 1e-12f);
        o.z = vmat[2][t] / fmaxf(snrm[2], 1e-12f);
        o.w = vmat[3][t] / fmaxf(snrm[3], 1e-12f);
        *(float4*)(out + ((size_t)(b * COUT + t)) * KTOP + g * 4) = o;
    }
}

extern "C" void kernel_launch(void* const* d_in, const int* in_sizes, int n_in,
                              void* d_out, int out_size, void* d_ws, size_t ws_size,
                              hipStream_t stream) {
    const float* lf   = (const float*)d_in[0];
    const float* pt   = (const float*)d_in[1];
    const float* attn = (const float*)d_in[2];
    const float* cw   = (const float*)d_in[3];
    const float* cb   = (const float*)d_in[4];
    const float* bg   = (const float*)d_in[5];
    const float* bb   = (const float*)d_in[6];
    const float* bm   = (const float*)d_in[7];
    const float* bvr  = (const float*)d_in[8];
    float* out = (float*)d_out;
    const int B = in_sizes[0] / (CF * HW);
    int* topk = (int*)d_ws;

    hipLaunchKernelGGL(topk_kernel, dim3(B), dim3(1024), 0, stream, attn, topk);
    hipLaunchKernelGGL(feat_kernel, dim3(KTOP / 4, B), dim3(128), 0, stream,
                       lf, pt, cw, cb, bg, bb, bm, bvr, topk, out);
}

// Round 6
// 24.630 us; speedup vs baseline: 1.4110x; 1.4110x over previous
//
#include <hip/hip_runtime.h>
#include <math.h>

#define IMG   112
#define HW    12544
#define GRID  16
#define DP    384
#define CF    128
#define CIN   512
#define COUT  128
#define KTOP  64
#define NHEADS 6
#define NBIN  2048   // 11-bit bins of the orderable key
#define CAP   2048   // candidate capacity (expected ~100-400 for Gaussian data)
#define NJ    12     // 12*1024 + 256 = 12544

// Replicate jax f32 sample position: fl32((i+0.5f)*fl32(16/112)) - 0.5f.
// Double product + truncation = exact f32 round-to-nearest multiply, not fusable.
__device__ __forceinline__ float sample_pos(int i) {
    const double inv = (double)(16.0f / 112.0f);
    float prod = (float)(((double)i + 0.5) * inv);
    return prod - 0.5f;
}

struct BL { int i0, i1; float w; };

__device__ __forceinline__ BL bl_coeff(int i) {
    float s = sample_pos(i);
    s = fminf(fmaxf(s, 0.0f), 15.0f);   // clamp FIRST -> clamp groups bit-identical
    int i0 = (int)s;
    if (i0 > GRID - 2) i0 = GRID - 2;
    BL r;
    r.i0 = i0;
    r.i1 = i0 + 1;
    r.w  = s - (float)i0;               // exact (Sterbenz)
    return r;
}

// Orderable transform: ascending finite float <-> ascending unsigned.
__device__ __forceinline__ unsigned ordkey(float f) {
    unsigned u = __float_as_uint(f);
    return u ^ ((u & 0x80000000u) ? 0xFFFFFFFFu : 0x80000000u);
}

// tc[i] = {bitcast(i0), w}; av[yi*16+xi] = {amean[yi][xi], amean[yi+1][xi]}.
// One b64 read each -> 4 LDS ops/pixel (2 tc + 2 av) vs 8. Arithmetic is
// bit-identical to the verified kernel (same values, same op order).
__device__ __forceinline__ unsigned bilin_key(const float2* av, const float2* tc,
                                              int idx) {
    int y = idx / IMG, x = idx - y * IMG;
    float2 ty = tc[y], tx = tc[x];
    int yi0 = __float_as_int(ty.x), xi0 = __float_as_int(tx.x);
    float wy = ty.y, wx = tx.y;
    float2 a0 = av[yi0 * GRID + xi0];
    float2 a1 = av[yi0 * GRID + xi0 + 1];
    float top = (1.0f - wx) * a0.x + wx * a1.x;
    float bot = (1.0f - wx) * a0.y + wx * a1.y;
    float v   = (1.0f - wy) * top + wy * bot;
    return ordkey(v);
}

// Fused: each block (g, b) redundantly computes batch b's top-64 (phase 1,
// identical to the verified two-kernel topk), then computes features for its
// own 4 pixels (phase 2, identical arithmetic to the verified feat kernel).
extern "C" __global__ void __launch_bounds__(1024)
fused_kernel(const float* __restrict__ attn, const float* __restrict__ lf,
             const float* __restrict__ pt, const float* __restrict__ cw,
             const float* __restrict__ cb, const float* __restrict__ bg,
             const float* __restrict__ bb, const float* __restrict__ bm,
             const float* __restrict__ bvr, float* __restrict__ out) {
    __shared__ float    amean[GRID * GRID];
    __shared__ float2   av[240];         // yi0 in 0..14
    __shared__ float2   tc[IMG];
    __shared__ unsigned hist[8][NBIN];   // 64 KB, per-wave-pair copies
    __shared__ unsigned wtot[16];
    __shared__ unsigned s_T;
    __shared__ int      s_nc;
    __shared__ unsigned candk[CAP];
    __shared__ int      candi[CAP];
    __shared__ int      topidx[KTOP];
    __shared__ __align__(16) float comb[4][CIN];   // 8 KB
    __shared__ __align__(16) float vmat[4][COUT];
    __shared__ float snrm[4];

    const int g = blockIdx.x;    // pixel group: 4 topk pixels
    const int b = blockIdx.y;    // batch
    const int t = threadIdx.x;
    const int lane = t & 63;
    const int wv = t >> 6;       // 0..15
    const int hc = wv >> 1;      // 8 histogram copies

    // ---------------- phase 1: top-64 for batch b ----------------
    if (t < 256) {
        float s = 0.0f;
        for (int h = 0; h < NHEADS; ++h)
            s += attn[(((size_t)b * NHEADS + h) << 8) + t];
        amean[t] = s * (1.0f / 6.0f);
    } else if (t < 256 + IMG) {
        int i = t - 256;
        BL c = bl_coeff(i);
        tc[i] = make_float2(__int_as_float(c.i0), c.w);
    }
    for (int i = t; i < 8 * NBIN; i += 1024) ((unsigned*)hist)[i] = 0;
    if (t == 0) s_nc = 0;
    __syncthreads();
    if (t < 240) av[t] = make_float2(amean[t], amean[t + 16]);
    __syncthreads();

    // 12.25 resized values per thread (bit-identical arithmetic). Lane->pixel
    // rotation decorrelates histogram bins within a wave.
    const int pt_ = (((t & 63) << 4) | (t >> 6)) & 1023;   // bijection on 0..1023
    unsigned lk[NJ];
    unsigned tailk = 0;
#pragma unroll
    for (int j = 0; j < NJ; ++j) {
        unsigned key = bilin_key(av, tc, j * 1024 + pt_);
        lk[j] = key;
        atomicAdd(&hist[hc][key >> 21], 1u);
    }
    if (t < 256) {
        tailk = bilin_key(av, tc, NJ * 1024 + t);
        atomicAdd(&hist[hc][tailk >> 21], 1u);
    }
    __syncthreads();

    // block-wide suffix scan over 2048 bins (2 bins per thread): find bin T
    // such that count(bin >= T) >= 64 > count(bin >= T+1)
    unsigned c0 = 0, c1 = 0;
    {
        const int bin0 = t * 2;
#pragma unroll
        for (int k = 0; k < 8; ++k) { c0 += hist[k][bin0]; c1 += hist[k][bin0 + 1]; }
    }
    const unsigned tot = c0 + c1;
    unsigned v = tot;   // inclusive suffix within wave
    for (int off = 1; off < 64; off <<= 1) {
        unsigned o = __shfl_down(v, off);
        if (lane + off < 64) v += o;
    }
    if (lane == 0) wtot[wv] = v;
    __syncthreads();
    unsigned add = 0;
    for (int w = wv + 1; w < 16; ++w) add += wtot[w];
    const unsigned S = v + add;          // count in bins >= t*2
    const unsigned above = S - tot;      // count in bins >= t*2+2
    const unsigned cum1 = above + c1;    // bins >= t*2+1
    if (cum1 >= KTOP && above < KTOP) s_T = (unsigned)(t * 2 + 1);
    const unsigned cum0 = cum1 + c0;     // bins >= t*2
    if (cum0 >= KTOP && cum1 < KTOP) s_T = (unsigned)(t * 2);
    __syncthreads();
    const unsigned T = s_T;

    // collect all candidates with bin >= T
#pragma unroll
    for (int j = 0; j < NJ; ++j) {
        unsigned key = lk[j];
        if ((key >> 21) >= T) {
            int sl = atomicAdd(&s_nc, 1);
            if (sl < CAP) { candk[sl] = key; candi[sl] = j * 1024 + pt_; }
        }
    }
    if (t < 256 && (tailk >> 21) >= T) {
        int sl = atomicAdd(&s_nc, 1);
        if (sl < CAP) { candk[sl] = tailk; candi[sl] = NJ * 1024 + t; }
    }
    __syncthreads();

    // exact stable rank select, 4 threads per candidate (rank depends only on
    // the candidate SET, so insertion order is irrelevant):
    // total order (key desc, idx asc) == jax.lax.top_k
    const int n = s_nc < CAP ? s_nc : CAP;
    const int q = t & 3;
    for (int c = t >> 2; c < n; c += 256) {
        unsigned myk = candk[c]; int myi = candi[c];
        int r = 0;
        for (int j2 = q; j2 < n; j2 += 4) {
            unsigned k2 = candk[j2];
            r += (k2 > myk) || (k2 == myk && candi[j2] < myi);
        }
        r += __shfl_xor(r, 1);
        r += __shfl_xor(r, 2);
        if (q == 0 && r < KTOP) topidx[r] = myi;
    }
    __syncthreads();

    // ---------------- phase 2: features for this block's 4 pixels ----------------
    int pidx[4];
#pragma unroll
    for (int i = 0; i < 4; ++i) pidx[i] = topidx[g * 4 + i];

    int   yi0[4], xi0[4];
    float wyv[4], wxv[4];
#pragma unroll
    for (int px = 0; px < 4; ++px) {
        const int idx = pidx[px];
        const int y = idx / IMG, x = idx - y * IMG;
        BL by = bl_coeff(y), bx = bl_coeff(x);
        yi0[px] = by.i0; xi0[px] = bx.i0; wyv[px] = by.w; wxv[px] = bx.w;
    }
    // stage comb[4][512]: thread -> (c = t&511, px = (t>>9)*2 + pp)
    {
        const int c = t & 511;
        const int ph = t >> 9;
        const float* ptb = pt + (size_t)b * 256 * DP;
#pragma unroll
        for (int pp = 0; pp < 2; ++pp) {
            const int px = ph * 2 + pp;
            float val;
            if (c < DP) {
                const int base = yi0[px] * GRID + xi0[px];
                float p00 = ptb[(size_t)base * DP + c];
                float p01 = ptb[(size_t)(base + 1) * DP + c];
                float p10 = ptb[(size_t)(base + GRID) * DP + c];
                float p11 = ptb[(size_t)(base + GRID + 1) * DP + c];
                float top = (1.0f - wxv[px]) * p00 + wxv[px] * p01;
                float bot = (1.0f - wxv[px]) * p10 + wxv[px] * p11;
                val = (1.0f - wyv[px]) * top + wyv[px] * bot;
            } else {
                val = lf[((size_t)b * CF + (c - DP)) * HW + pidx[px]];
            }
            comb[px][c] = val;
        }
    }
    __syncthreads();

    // GEMV (threads 0..511): 4 lanes per output channel, coalesced 64B weight
    // lines, comb reads are LDS broadcasts (16 groups share each address).
    if (t < 512) {
        const int ch = t >> 2, l = t & 3;
        const float* wrow = cw + (size_t)ch * CIN + l * 4;
        float a0 = 0.f, a1 = 0.f, a2 = 0.f, a3 = 0.f;
#pragma unroll 4
        for (int i = 0; i < 32; ++i) {
            float4 w4 = *(const float4*)(wrow + i * 16);
            float4 q0 = *(const float4*)(&comb[0][i * 16 + l * 4]);
            float4 q1 = *(const float4*)(&comb[1][i * 16 + l * 4]);
            float4 q2 = *(const float4*)(&comb[2][i * 16 + l * 4]);
            float4 q3 = *(const float4*)(&comb[3][i * 16 + l * 4]);
            a0 += w4.x * q0.x + w4.y * q0.y + w4.z * q0.z + w4.w * q0.w;
            a1 += w4.x * q1.x + w4.y * q1.y + w4.z * q1.z + w4.w * q1.w;
            a2 += w4.x * q2.x + w4.y * q2.y + w4.z * q2.z + w4.w * q2.w;
            a3 += w4.x * q3.x + w4.y * q3.y + w4.z * q3.z + w4.w * q3.w;
        }
        a0 += __shfl_xor(a0, 1); a0 += __shfl_xor(a0, 2);
        a1 += __shfl_xor(a1, 1); a1 += __shfl_xor(a1, 2);
        a2 += __shfl_xor(a2, 1); a2 += __shfl_xor(a2, 2);
        a3 += __shfl_xor(a3, 1); a3 += __shfl_xor(a3, 2);
        if (l == 0) {
            float scale = bg[ch] / sqrtf(bvr[ch] + 1e-5f);
            float shift = bb[ch] - bm[ch] * scale;
            float base  = cb[ch];
            vmat[0][ch] = fmaxf((base + a0) * scale + shift, 0.0f);
            vmat[1][ch] = fmaxf((base + a1) * scale + shift, 0.0f);
            vmat[2][ch] = fmaxf((base + a2) * scale + shift, 0.0f);
            vmat[3][ch] = fmaxf((base + a3) * scale + shift, 0.0f);
        }
    }
    __syncthreads();

    // L2 norm per pixel (waves 0-3, one pixel each)
    if (wv < 4) {
        float x0 = vmat[wv][lane], x1 = vmat[wv][lane + 64];
        float ss = x0 * x0 + x1 * x1;
        for (int off = 32; off > 0; off >>= 1) ss += __shfl_xor(ss, off);
        if (lane == 0) snrm[wv] = sqrtf(ss);
    }
    __syncthreads();

    if (t < 512) {
        const int px = t & 3, c2 = t >> 2;
        out[((size_t)(b * COUT + c2)) * KTOP + g * 4 + px] =
            vmat[px][c2] / fmaxf(snrm[px], 1e-12f);
    }
}

extern "C" void kernel_launch(void* const* d_in, const int* in_sizes, int n_in,
                              void* d_out, int out_size, void* d_ws, size_t ws_size,
                              hipStream_t stream) {
    const float* lf   = (const float*)d_in[0];
    const float* pt   = (const float*)d_in[1];
    const float* attn = (const float*)d_in[2];
    const float* cw   = (const float*)d_in[3];
    const float* cb   = (const float*)d_in[4];
    const float* bg   = (const float*)d_in[5];
    const float* bb   = (const float*)d_in[6];
    const float* bm   = (const float*)d_in[7];
    const float* bvr  = (const float*)d_in[8];
    float* out = (float*)d_out;
    const int B = in_sizes[0] / (CF * HW);

    hipLaunchKernelGGL(fused_kernel, dim3(KTOP / 4, B), dim3(1024), 0, stream,
                       attn, lf, pt, cw, cb, bg, bb, bm, bvr, out);
}